// Round 2
// baseline (87.905 us; speedup 1.0000x reference)
//
#include <hip/hip_runtime.h>

#define LRN 256
#define HRN 1024
#define SCALE (255.0f/1023.0f)

typedef float v2 __attribute__((ext_vector_type(2)));

// ---- workspace layout ----
// [0,4K)      : int    lutA[1024]           per-coord anchor
// [4K,52K)    : float4 lutW[1024][3]        per-coord weights (minus, plus, full)
// [64K, ...)  : v2     AB[3][256][256]      guided-filter (A,b) plane
#define WS_LUTW 4096
#define WS_AB   65536

// Anchor: lr index of the lowest tap of any pattern at out-coord u.
__device__ inline int anchor_of(int u) {
    int k = min(max(u - 4, 0), HRN - 1);
    float t = (float)k * SCALE;
    int i = (int)t; if (i > LRN - 2) i = LRN - 2;
    return i;
}

// Accumulated 4-tap lr weights for hr taps k0..k1 (clamped), relative to anchor a.
__device__ inline float4 mkw(int k0, int k1, int a) {
    float4 w = make_float4(0.f, 0.f, 0.f, 0.f);
    for (int k = k0; k <= k1; ++k) {
        int kc = min(max(k, 0), HRN - 1);
        float t = (float)kc * SCALE;
        int i = (int)t; if (i > LRN - 2) i = LRN - 2;
        float f = t - (float)i;
        int off = i - a;                 // in [0,2]
        float wa = 1.0f - f, wb = f;
        w.x += (off == 0) ? wa : 0.0f;
        w.y += (off == 1) ? wa : ((off == 0) ? wb : 0.0f);
        w.z += (off == 2) ? wa : ((off == 1) ? wb : 0.0f);
        w.w += (off == 2) ? wb : 0.0f;
    }
    return w;
}

// ============================================================================
// Kernel 1: LUT (1024 entries) + guided-filter (A,b) plane at LR.
// ============================================================================
__global__ __launch_bounds__(256, 4) void lr_kernel(
    const float* __restrict__ lrx, const float* __restrict__ lry,
    float* __restrict__ ws)
{
    __shared__ float4 sV[24][40];
    __shared__ float4 sHS[24][32];

    const int c  = blockIdx.z;
    const int X0 = blockIdx.x * 32, Y0 = blockIdx.y * 16;
    const int tid = threadIdx.y * 32 + threadIdx.x;
    const float* px = lrx + c * LRN * LRN;
    const float* py = lry + c * LRN * LRN;

    // one-off: weight LUT (8 blocks x 128 threads cover 1024 coords)
    if (c == 0 && blockIdx.y == 0 && tid < 128) {
        int u = blockIdx.x * 128 + tid;
        int a = anchor_of(u);
        ((int*)ws)[u] = a;
        float4* w = (float4*)((char*)ws + WS_LUTW) + u * 3;
        w[0] = mkw(u - 4, u,     a);   // minus side (L / T)
        w[1] = mkw(u,     u + 4, a);   // plus side  (R / B)
        w[2] = mkw(u - 4, u + 4, a);   // full       (F)
    }

    for (int i = tid; i < 24 * 40; i += 256) {
        int r = i / 40, cc = i - r * 40;
        int gy = min(max(Y0 - 4 + r, 0), LRN - 1);
        int gx = min(max(X0 - 4 + cc, 0), LRN - 1);
        float xv = px[gy * LRN + gx];
        float yv = py[gy * LRN + gx];
        sV[r][cc] = make_float4(xv, yv, xv * yv, xv * xv);
    }
    __syncthreads();

    for (int i = tid; i < 24 * 32; i += 256) {
        int r = i / 32, cc = i & 31;
        float4 s = sV[r][cc];
        #pragma unroll
        for (int k = 1; k < 9; ++k) {
            float4 v = sV[r][cc + k];
            s.x += v.x; s.y += v.y; s.z += v.z; s.w += v.w;
        }
        sHS[r][cc] = s;
    }
    __syncthreads();

    v2* ab_out = (v2*)((char*)ws + WS_AB);
    for (int i = tid; i < 16 * 32; i += 256) {
        int r = i / 32, cc = i & 31;
        float4 s = sHS[r][cc];
        #pragma unroll
        for (int k = 1; k < 9; ++k) {
            float4 v = sHS[r + k][cc];
            s.x += v.x; s.y += v.y; s.z += v.z; s.w += v.w;
        }
        const float inv81 = 1.0f / 81.0f;
        float mx = s.x * inv81, my = s.y * inv81;
        float cov = s.z * inv81 - mx * my;
        float var = s.w * inv81 - mx * mx;
        float A = cov / (var + 2.0f);
        float B = my - A * mx;
        v2 ab; ab.x = A; ab.y = B;
        ab_out[(c * LRN + (Y0 + r)) * LRN + X0 + cc] = ab;
    }
}

// ============================================================================
// Kernel 2: upsample + 8-direction side-window stencil.
// Tile: 64 cols x 32 rows, block (64,4); each thread walks 8 rows of one col.
// Horizontal mixes (L/R/F) precomputed per (lr_row, hr_col) in LDS; vertical
// taps held in registers across the row walk (anchor advances <=1/row).
// ============================================================================
#define TX 64
#define TYV 32
#define WROWS 8
#define LRC 20             // lr cols spanned by 64 hr cols + taps
#define LRR 12             // lr rows spanned by 32 hr rows + taps

__global__ __launch_bounds__(256, 6) void hr_kernel(
    const float* __restrict__ hrx, const float* __restrict__ ws,
    float* __restrict__ out)
{
    __shared__ v2     sHL[LRR][TX];     // horizontal "minus" mix of (A,b)
    __shared__ v2     sHR[LRR][TX];     // horizontal "plus"  mix
    __shared__ v2     sHF[LRR][TX];     // horizontal "full"  mix
    __shared__ v2     sAB[LRR][LRC];    // lr (A,b) patch
    __shared__ float4 sXW[TX][3];       // per-col weights: L,R,F
    __shared__ int    sXA[TX];
    __shared__ float4 sYW[TYV][3];      // per-row weights: T,B,F
    __shared__ int    sYA[TYV];

    const int c  = blockIdx.z;
    const int X0 = blockIdx.x * TX, Y0 = blockIdx.y * TYV;
    const int tid = threadIdx.y * TX + threadIdx.x;

    const int*    lutA = (const int*)ws;
    const float4* lutW = (const float4*)((const char*)ws + WS_LUTW);
    const v2*     AB   = (const v2*)((const char*)ws + WS_AB) + c * LRN * LRN;

    const int rowbase = lutA[Y0];
    const int colbase = lutA[X0];

    // phase 0: LUT slices + AB patch
    if (tid < TX) {
        int u = X0 + tid;
        sXA[tid] = lutA[u] - colbase;
        sXW[tid][0] = lutW[u * 3 + 0];
        sXW[tid][1] = lutW[u * 3 + 1];
        sXW[tid][2] = lutW[u * 3 + 2];
    } else if (tid < TX + TYV) {
        int r = tid - TX, u = Y0 + r;
        sYA[r] = lutA[u] - rowbase;
        sYW[r][0] = lutW[u * 3 + 0];
        sYW[r][1] = lutW[u * 3 + 1];
        sYW[r][2] = lutW[u * 3 + 2];
    }
    for (int i = tid; i < LRR * LRC; i += 256) {
        int r = i / LRC, cc = i - r * LRC;
        int gy = min(rowbase + r, LRN - 1);
        int gx = min(colbase + cc, LRN - 1);
        sAB[r][cc] = AB[gy * LRN + gx];
    }
    __syncthreads();

    // phase D': horizontal 4-tap mixes per (lr_row, hr_col)
    for (int i = tid; i < LRR * TX; i += 256) {
        int r = i >> 6, x = i & 63;
        int c0 = sXA[x];
        float4 wL = sXW[x][0], wR = sXW[x][1], wF = sXW[x][2];
        v2 a0 = sAB[r][c0],     a1 = sAB[r][c0 + 1];
        v2 a2 = sAB[r][c0 + 2], a3 = sAB[r][c0 + 3];
        v2 hl, hr_, hf;
        hl  = a0 * wL.x;
        hl  = __builtin_elementwise_fma((v2)(wL.y), a1, hl);
        hl  = __builtin_elementwise_fma((v2)(wL.z), a2, hl);
        hl  = __builtin_elementwise_fma((v2)(wL.w), a3, hl);
        hr_ = a0 * wR.x;
        hr_ = __builtin_elementwise_fma((v2)(wR.y), a1, hr_);
        hr_ = __builtin_elementwise_fma((v2)(wR.z), a2, hr_);
        hr_ = __builtin_elementwise_fma((v2)(wR.w), a3, hr_);
        hf  = a0 * wF.x;
        hf  = __builtin_elementwise_fma((v2)(wF.y), a1, hf);
        hf  = __builtin_elementwise_fma((v2)(wF.z), a2, hf);
        hf  = __builtin_elementwise_fma((v2)(wF.w), a3, hf);
        sHL[r][x] = hl; sHR[r][x] = hr_; sHF[r][x] = hf;
    }
    __syncthreads();

    // phase E: column walk, vertical combine + argmin
    const int tx = threadIdx.x, tyw = threadIdx.y;
    const int row0 = tyw * WROWS;
    const float i45 = 1.0f / 45.0f, i25 = 1.0f / 25.0f;
    const float* hp = hrx + (c * HRN + Y0 + row0) * HRN + X0 + tx;
    float*       op = out + (c * HRN + Y0 + row0) * HRN + X0 + tx;

    int rap = sYA[row0];                        // wave-uniform
    v2 hL0 = sHL[rap][tx],     hL1 = sHL[rap + 1][tx];
    v2 hL2 = sHL[rap + 2][tx], hL3 = sHL[rap + 3][tx];
    v2 hR0 = sHR[rap][tx],     hR1 = sHR[rap + 1][tx];
    v2 hR2 = sHR[rap + 2][tx], hR3 = sHR[rap + 3][tx];
    v2 hF0 = sHF[rap][tx],     hF1 = sHF[rap + 1][tx];
    v2 hF2 = sHF[rap + 2][tx], hF3 = sHF[rap + 3][tx];

    #pragma unroll
    for (int j = 0; j < WROWS; ++j) {
        const int yr = row0 + j;
        const int ra = sYA[yr];                 // wave-uniform broadcast
        if (ra != rap) {                        // advances by at most 1
            hL0 = hL1; hL1 = hL2; hL2 = hL3; hL3 = sHL[ra + 3][tx];
            hR0 = hR1; hR1 = hR2; hR2 = hR3; hR3 = sHR[ra + 3][tx];
            hF0 = hF1; hF1 = hF2; hF2 = hF3; hF3 = sHF[ra + 3][tx];
            rap = ra;
        }
        const float4 wT = sYW[yr][0], wB = sYW[yr][1], wFv = sYW[yr][2];

        v2 aL = 0, aR = 0, aU = 0, aD = 0;
        v2 aNW = 0, aNE = 0, aSW = 0, aSE = 0;
        #define TAPK(WT, WB, WF, HL, HR_, HF)                         \
            aU  = __builtin_elementwise_fma((v2)(WT), HF,  aU);       \
            aD  = __builtin_elementwise_fma((v2)(WB), HF,  aD);       \
            aL  = __builtin_elementwise_fma((v2)(WF), HL,  aL);       \
            aR  = __builtin_elementwise_fma((v2)(WF), HR_, aR);       \
            aNW = __builtin_elementwise_fma((v2)(WT), HL,  aNW);      \
            aNE = __builtin_elementwise_fma((v2)(WT), HR_, aNE);      \
            aSW = __builtin_elementwise_fma((v2)(WB), HL,  aSW);      \
            aSE = __builtin_elementwise_fma((v2)(WB), HR_, aSE);
        TAPK(wT.x, wB.x, wFv.x, hL0, hR0, hF0)
        TAPK(wT.y, wB.y, wFv.y, hL1, hR1, hF1)
        TAPK(wT.z, wB.z, wFv.z, hL2, hR2, hF2)
        TAPK(wT.w, wB.w, wFv.w, hL3, hR3, hF3)
        #undef TAPK

        float xv = hp[j * HRN];

        float d0 = fmaf(i45, fmaf(aL.x,  xv, aL.y),  -xv); // L
        float d1 = fmaf(i45, fmaf(aR.x,  xv, aR.y),  -xv); // R
        float d2 = fmaf(i45, fmaf(aU.x,  xv, aU.y),  -xv); // U
        float d3 = fmaf(i45, fmaf(aD.x,  xv, aD.y),  -xv); // D
        float d4 = fmaf(i25, fmaf(aNW.x, xv, aNW.y), -xv); // NW
        float d5 = fmaf(i25, fmaf(aNE.x, xv, aNE.y), -xv); // NE
        float d6 = fmaf(i25, fmaf(aSW.x, xv, aSW.y), -xv); // SW
        float d7 = fmaf(i25, fmaf(aSE.x, xv, aSE.y), -xv); // SE

        float a0 = fabsf(d0), a1 = fabsf(d1), a2 = fabsf(d2), a3 = fabsf(d3);
        float a4 = fabsf(d4), a5 = fabsf(d5), a6 = fabsf(d6), a7 = fabsf(d7);
        bool c01 = a0 <= a1; float w01 = c01 ? d0 : d1; float m01 = c01 ? a0 : a1;
        bool c23 = a2 <= a3; float w23 = c23 ? d2 : d3; float m23 = c23 ? a2 : a3;
        bool c45 = a4 <= a5; float w45 = c45 ? d4 : d5; float m45 = c45 ? a4 : a5;
        bool c67 = a6 <= a7; float w67 = c67 ? d6 : d7; float m67 = c67 ? a6 : a7;
        bool cA_ = m01 <= m23; float wA = cA_ ? w01 : w23; float mA = cA_ ? m01 : m23;
        bool cB_ = m45 <= m67; float wB_ = cB_ ? w45 : w67; float mB = cB_ ? m45 : m67;
        float bd = (mA <= mB) ? wA : wB_;

        float res = __builtin_amdgcn_fmed3f(truncf(bd + xv), 0.0f, 255.0f);
        op[j * HRN] = res;
    }
}

extern "C" void kernel_launch(void* const* d_in, const int* in_sizes, int n_in,
                              void* d_out, int out_size, void* d_ws, size_t ws_size,
                              hipStream_t stream) {
    const float* lrx = (const float*)d_in[0];
    const float* lry = (const float*)d_in[1];
    const float* hrx = (const float*)d_in[2];
    (void)d_in[3]; (void)in_sizes; (void)n_in; (void)out_size; (void)ws_size;

    float* ws   = (float*)d_ws;
    float* outp = (float*)d_out;

    lr_kernel<<<dim3(LRN / 32, LRN / 16, 3), dim3(32, 8), 0, stream>>>(lrx, lry, ws);
    hr_kernel<<<dim3(HRN / TX, HRN / TYV, 3), dim3(TX, 4), 0, stream>>>(hrx, ws, outp);
}

// Round 3
// 83.530 us; speedup vs baseline: 1.0524x; 1.0524x over previous
//
#include <hip/hip_runtime.h>

#define LRN 256
#define HRN 1024
#define SCALE (255.0f/1023.0f)

typedef float v2 __attribute__((ext_vector_type(2)));

// Single fused kernel, one dispatch.
// Tile: 64 cols x 32 rows of HR pixels, block (64,4); wave = one full HR row.
// Per block: stage lr stats (GRxGC, rep-pad clamped) -> 9-tap h sums -> 9-tap v
// sums + guided-filter finalize (A,b) -> horizontal 4-tap mixes per hr col ->
// column walk with register-resident vertical taps + argmin.
#define TX 64
#define TYV 32
#define WROWS 8
#define LRC 20             // lr cols of AB needed (span of 64 hr cols + taps)
#define LRR 12             // lr rows of AB needed (span of 32 hr rows + taps)
#define GC (LRC + 8)       // 28 staged lr input cols (box halo)
#define GR (LRR + 8)       // 20 staged lr input rows

// Anchor: lr index of the lowest tap of any pattern at out-coord u.
__device__ inline int anchor_of(int u) {
    int k = min(max(u - 4, 0), HRN - 1);
    float t = (float)k * SCALE;
    int i = (int)t; if (i > LRN - 2) i = LRN - 2;
    return i;
}

// Accumulated 4-tap lr weights for hr taps k0..k1 (clamped), relative to anchor a.
// Effective filter = (box over hr taps) o (bilinear align_corners upsample).
__device__ inline float4 mkw(int k0, int k1, int a) {
    float4 w = make_float4(0.f, 0.f, 0.f, 0.f);
    for (int k = k0; k <= k1; ++k) {
        int kc = min(max(k, 0), HRN - 1);
        float t = (float)kc * SCALE;
        int i = (int)t; if (i > LRN - 2) i = LRN - 2;
        float f = t - (float)i;
        int off = i - a;                 // in [0,2]
        float wa = 1.0f - f, wb = f;
        w.x += (off == 0) ? wa : 0.0f;
        w.y += (off == 1) ? wa : ((off == 0) ? wb : 0.0f);
        w.z += (off == 2) ? wa : ((off == 1) ? wb : 0.0f);
        w.w += (off == 2) ? wb : 0.0f;
    }
    return w;
}

__global__ __launch_bounds__(256, 6) void fused_kernel(
    const float* __restrict__ lrx, const float* __restrict__ lry,
    const float* __restrict__ hrx, float* __restrict__ out)
{
    // region1 aliased: phases A-C use sV(8960)+sHS(6400)=15360 B;
    // phases D-E use sHL/sHR/sHF = 3*6144 = 18432 B.
    __shared__ alignas(16) char region1[18432];
    float4 (*sV)[GC]   = reinterpret_cast<float4(*)[GC]>(region1);
    float4 (*sHS)[LRC] = reinterpret_cast<float4(*)[LRC]>(region1 + GR * GC * 16);
    v2 (*sHL)[TX] = reinterpret_cast<v2(*)[TX]>(region1);
    v2 (*sHR)[TX] = reinterpret_cast<v2(*)[TX]>(region1 + 6144);
    v2 (*sHF)[TX] = reinterpret_cast<v2(*)[TX]>(region1 + 12288);

    __shared__ v2     sAB[LRR][LRC];    // lr (A,b) patch
    __shared__ float4 sXWL[TX], sXWR[TX], sXWF[TX];   // per-col weights (split: conflict-free)
    __shared__ int    sXA[TX];
    __shared__ float4 sYWT[TYV], sYWB[TYV], sYWF[TYV]; // per-row weights
    __shared__ int    sYA[TYV];

    const int c  = blockIdx.z;
    const int X0 = blockIdx.x * TX, Y0 = blockIdx.y * TYV;
    const int tid = threadIdx.y * TX + threadIdx.x;
    const float* px = lrx + c * LRN * LRN;
    const float* py = lry + c * LRN * LRN;

    const int rowbase = anchor_of(Y0);
    const int colbase = anchor_of(X0);

    // phase 0: weight LUTs (cols: threads 0..63, rows: threads 64..95)
    if (tid < TX) {
        int x = X0 + tid;
        int a = anchor_of(x);
        sXA[tid] = a - colbase;
        sXWL[tid] = mkw(x - 4, x,     a);
        sXWR[tid] = mkw(x,     x + 4, a);
        sXWF[tid] = mkw(x - 4, x + 4, a);
    } else if (tid < TX + TYV) {
        int r = tid - TX;
        int y = Y0 + r;
        int a = anchor_of(y);
        sYA[r] = a - rowbase;
        sYWT[r] = mkw(y - 4, y,     a);
        sYWB[r] = mkw(y,     y + 4, a);
        sYWF[r] = mkw(y - 4, y + 4, a);
    }

    // phase A: stage lr stats region (GR x GC), coords clamped (rep-pad)
    for (int i = tid; i < GR * GC; i += 256) {
        int r = i / GC, cc = i - r * GC;
        int gy = min(max(rowbase - 4 + r, 0), LRN - 1);
        int gx = min(max(colbase - 4 + cc, 0), LRN - 1);
        float xv = px[gy * LRN + gx];
        float yv = py[gy * LRN + gx];
        sV[r][cc] = make_float4(xv, yv, xv * yv, xv * xv);
    }
    __syncthreads();

    // phase B: horizontal 9-tap sums (GR rows x LRC cols)
    for (int i = tid; i < GR * LRC; i += 256) {
        int r = i / LRC, cc = i - r * LRC;
        float4 s = sV[r][cc];
        #pragma unroll
        for (int k = 1; k < 9; ++k) {
            float4 v = sV[r][cc + k];
            s.x += v.x; s.y += v.y; s.z += v.z; s.w += v.w;
        }
        sHS[r][cc] = s;
    }
    __syncthreads();

    // phase C: vertical 9-tap + finalize A,b (LRR x LRC)
    for (int i = tid; i < LRR * LRC; i += 256) {
        int r = i / LRC, cc = i - r * LRC;
        float4 s = sHS[r][cc];
        #pragma unroll
        for (int k = 1; k < 9; ++k) {
            float4 v = sHS[r + k][cc];
            s.x += v.x; s.y += v.y; s.z += v.z; s.w += v.w;
        }
        const float inv81 = 1.0f / 81.0f;
        float mx = s.x * inv81, my = s.y * inv81;
        float cov = s.z * inv81 - mx * my;
        float var = s.w * inv81 - mx * mx;
        float A = cov / (var + 2.0f);
        float B = my - A * mx;
        v2 ab; ab.x = A; ab.y = B;
        sAB[r][cc] = ab;
    }
    __syncthreads();   // sV/sHS dead after this; region1 reused for sHL/sHR/sHF

    // phase D': horizontal 4-tap mixes per (lr_row, hr_col)
    for (int i = tid; i < LRR * TX; i += 256) {
        int r = i >> 6, x = i & 63;
        int c0 = sXA[x];
        float4 wL = sXWL[x], wR = sXWR[x], wF = sXWF[x];
        v2 a0 = sAB[r][c0],     a1 = sAB[r][c0 + 1];
        v2 a2 = sAB[r][c0 + 2], a3 = sAB[r][c0 + 3];
        v2 hl, hr_, hf;
        hl  = a0 * wL.x;
        hl  = __builtin_elementwise_fma((v2)(wL.y), a1, hl);
        hl  = __builtin_elementwise_fma((v2)(wL.z), a2, hl);
        hl  = __builtin_elementwise_fma((v2)(wL.w), a3, hl);
        hr_ = a0 * wR.x;
        hr_ = __builtin_elementwise_fma((v2)(wR.y), a1, hr_);
        hr_ = __builtin_elementwise_fma((v2)(wR.z), a2, hr_);
        hr_ = __builtin_elementwise_fma((v2)(wR.w), a3, hr_);
        hf  = a0 * wF.x;
        hf  = __builtin_elementwise_fma((v2)(wF.y), a1, hf);
        hf  = __builtin_elementwise_fma((v2)(wF.z), a2, hf);
        hf  = __builtin_elementwise_fma((v2)(wF.w), a3, hf);
        sHL[r][x] = hl; sHR[r][x] = hr_; sHF[r][x] = hf;
    }
    __syncthreads();

    // phase E: column walk, vertical combine + argmin
    const int tx = threadIdx.x, tyw = threadIdx.y;
    const int row0 = tyw * WROWS;
    const float i45 = 1.0f / 45.0f, i25 = 1.0f / 25.0f;
    const float* hp = hrx + (c * HRN + Y0 + row0) * HRN + X0 + tx;
    float*       op = out + (c * HRN + Y0 + row0) * HRN + X0 + tx;

    int rap = sYA[row0];                        // wave-uniform
    v2 hL0 = sHL[rap][tx],     hL1 = sHL[rap + 1][tx];
    v2 hL2 = sHL[rap + 2][tx], hL3 = sHL[rap + 3][tx];
    v2 hR0 = sHR[rap][tx],     hR1 = sHR[rap + 1][tx];
    v2 hR2 = sHR[rap + 2][tx], hR3 = sHR[rap + 3][tx];
    v2 hF0 = sHF[rap][tx],     hF1 = sHF[rap + 1][tx];
    v2 hF2 = sHF[rap + 2][tx], hF3 = sHF[rap + 3][tx];

    #pragma unroll
    for (int j = 0; j < WROWS; ++j) {
        const int yr = row0 + j;
        const int ra = sYA[yr];                 // wave-uniform broadcast
        if (ra != rap) {                        // advances by at most 1
            hL0 = hL1; hL1 = hL2; hL2 = hL3; hL3 = sHL[ra + 3][tx];
            hR0 = hR1; hR1 = hR2; hR2 = hR3; hR3 = sHR[ra + 3][tx];
            hF0 = hF1; hF1 = hF2; hF2 = hF3; hF3 = sHF[ra + 3][tx];
            rap = ra;
        }
        const float4 wT = sYWT[yr], wB = sYWB[yr], wFv = sYWF[yr];

        v2 aL = 0, aR = 0, aU = 0, aD = 0;
        v2 aNW = 0, aNE = 0, aSW = 0, aSE = 0;
        #define TAPK(WT, WB, WF, HL, HR_, HF)                         \
            aU  = __builtin_elementwise_fma((v2)(WT), HF,  aU);       \
            aD  = __builtin_elementwise_fma((v2)(WB), HF,  aD);       \
            aL  = __builtin_elementwise_fma((v2)(WF), HL,  aL);       \
            aR  = __builtin_elementwise_fma((v2)(WF), HR_, aR);       \
            aNW = __builtin_elementwise_fma((v2)(WT), HL,  aNW);      \
            aNE = __builtin_elementwise_fma((v2)(WT), HR_, aNE);      \
            aSW = __builtin_elementwise_fma((v2)(WB), HL,  aSW);      \
            aSE = __builtin_elementwise_fma((v2)(WB), HR_, aSE);
        TAPK(wT.x, wB.x, wFv.x, hL0, hR0, hF0)
        TAPK(wT.y, wB.y, wFv.y, hL1, hR1, hF1)
        TAPK(wT.z, wB.z, wFv.z, hL2, hR2, hF2)
        TAPK(wT.w, wB.w, wFv.w, hL3, hR3, hF3)
        #undef TAPK

        float xv = hp[j * HRN];

        float d0 = fmaf(i45, fmaf(aL.x,  xv, aL.y),  -xv); // L
        float d1 = fmaf(i45, fmaf(aR.x,  xv, aR.y),  -xv); // R
        float d2 = fmaf(i45, fmaf(aU.x,  xv, aU.y),  -xv); // U
        float d3 = fmaf(i45, fmaf(aD.x,  xv, aD.y),  -xv); // D
        float d4 = fmaf(i25, fmaf(aNW.x, xv, aNW.y), -xv); // NW
        float d5 = fmaf(i25, fmaf(aNE.x, xv, aNE.y), -xv); // NE
        float d6 = fmaf(i25, fmaf(aSW.x, xv, aSW.y), -xv); // SW
        float d7 = fmaf(i25, fmaf(aSE.x, xv, aSE.y), -xv); // SE

        float a0 = fabsf(d0), a1 = fabsf(d1), a2 = fabsf(d2), a3 = fabsf(d3);
        float a4 = fabsf(d4), a5 = fabsf(d5), a6 = fabsf(d6), a7 = fabsf(d7);
        bool c01 = a0 <= a1; float w01 = c01 ? d0 : d1; float m01 = c01 ? a0 : a1;
        bool c23 = a2 <= a3; float w23 = c23 ? d2 : d3; float m23 = c23 ? a2 : a3;
        bool c45 = a4 <= a5; float w45 = c45 ? d4 : d5; float m45 = c45 ? a4 : a5;
        bool c67 = a6 <= a7; float w67 = c67 ? d6 : d7; float m67 = c67 ? a6 : a7;
        bool cA_ = m01 <= m23; float wA = cA_ ? w01 : w23; float mA = cA_ ? m01 : m23;
        bool cB_ = m45 <= m67; float wB_ = cB_ ? w45 : w67; float mB = cB_ ? m45 : m67;
        float bd = (mA <= mB) ? wA : wB_;

        float res = __builtin_amdgcn_fmed3f(truncf(bd + xv), 0.0f, 255.0f);
        op[j * HRN] = res;
    }
}

extern "C" void kernel_launch(void* const* d_in, const int* in_sizes, int n_in,
                              void* d_out, int out_size, void* d_ws, size_t ws_size,
                              hipStream_t stream) {
    const float* lrx = (const float*)d_in[0];
    const float* lry = (const float*)d_in[1];
    const float* hrx = (const float*)d_in[2];
    (void)d_in[3]; (void)in_sizes; (void)n_in; (void)out_size;
    (void)d_ws; (void)ws_size;

    float* outp = (float*)d_out;
    fused_kernel<<<dim3(HRN / TX, HRN / TYV, 3), dim3(TX, 4), 0, stream>>>(lrx, lry, hrx, outp);
}